// Round 7
// baseline (379.594 us; speedup 1.0000x reference)
//
#include <hip/hip_runtime.h>
#include <hip/hip_bf16.h>
#include <stdint.h>

#define B_DIM 8
#define L_DIM 512
#define D_DIM 1024
#define S_DIM 6144
#define M_DIM (B_DIM * S_DIM)       // 49152
#define NCHUNK 8
#define CHUNK (L_DIM / NCHUNK)      // 64
#define CSB (513 * 1024)            // floats per batch in cs ([L+1][D])

typedef __attribute__((ext_vector_type(8))) short short8;
typedef __attribute__((ext_vector_type(4))) float f32x4;
typedef __attribute__((ext_vector_type(8))) unsigned short us8;

__device__ __forceinline__ unsigned short f2bf(float f) {
    unsigned int u = __float_as_uint(f);
    u += 0x7FFFu + ((u >> 16) & 1u);
    return (unsigned short)(u >> 16);
}

// ---------------- Phase 1a: chunk_sums + wconv fused (independent work) ----
__global__ __launch_bounds__(256) void prep_fused(const float* __restrict__ h,
                                                  float* __restrict__ csum,
                                                  const float* __restrict__ W,
                                                  unsigned short* __restrict__ Wbf) {
    if (blockIdx.x < 256) {
        // chunk_sums: csum[b][c][d] = sum over chunk c of h
        int tid = blockIdx.x * 256 + threadIdx.x;   // 65536 total
        int d = tid & 1023;
        int c = (tid >> 10) & 7;
        int b = tid >> 13;
        const float* hp = h + ((size_t)b * L_DIM + c * CHUNK) * D_DIM + d;
        float s = 0.f;
        #pragma unroll 8
        for (int i = 0; i < CHUNK; ++i) s += hp[(size_t)i * D_DIM];
        csum[tid] = s;
    } else {
        // wconv: W fp32 -> bf16 bits
        int tid = (blockIdx.x - 256) * 256 + threadIdx.x;   // 131072 total
        const float4* p = (const float4*)(W + (size_t)tid * 8);
        float4 a = p[0], c = p[1];
        us8 o;
        o[0] = f2bf(a.x); o[1] = f2bf(a.y); o[2] = f2bf(a.z); o[3] = f2bf(a.w);
        o[4] = f2bf(c.x); o[5] = f2bf(c.y); o[6] = f2bf(c.z); o[7] = f2bf(c.w);
        *(us8*)&Wbf[(size_t)tid * 8] = o;
    }
}

// ---------------- Phase 1b: build cs (exclusive prefix, L+1 rows) ----------
__global__ __launch_bounds__(256) void build_cs(const float* __restrict__ h,
                                                const float* __restrict__ csum,
                                                float* __restrict__ cs) {
    int tid = blockIdx.x * 256 + threadIdx.x;   // 65536 total
    int d = tid & 1023;
    int c = (tid >> 10) & 7;
    int b = tid >> 13;
    float p = 0.f;
    for (int cc = 0; cc < c; ++cc)
        p += csum[(b << 13) + (cc << 10) + d];
    const float* hp = h + ((size_t)b * L_DIM + c * CHUNK) * D_DIM + d;
    float* cp = cs + ((size_t)b * (L_DIM + 1) + c * CHUNK) * D_DIM + d;
    if (c == 0) cp[0] = 0.f;
    #pragma unroll 8
    for (int i = 0; i < CHUNK; ++i) {
        p += hp[(size_t)i * D_DIM];
        cp[(size_t)(i + 1) * D_DIM] = p;
    }
}

// ---------------- Phase 2: span_rep -> bf16 (paid ONCE: 393MB cs-ends read) -
__global__ __launch_bounds__(256) void spanrep(const float* __restrict__ cs,
                                               const int* __restrict__ span_idx,
                                               unsigned short* __restrict__ rep) {
    int tid = blockIdx.x * 256 + threadIdx.x;   // 6,291,456 total
    int d8 = tid & 127;
    int bs = tid >> 7;                           // 0..49151
    int b = bs / S_DIM;
    int2 se = ((const int2*)span_idx)[bs];
    int st = min(max(se.x, 0), L_DIM - 1);
    int en = min(max(se.y, 0), L_DIM - 1);
    bool valid = st <= en;
    float inv = valid ? 1.0f / (float)(en - st + 1) : 0.0f;
    const float* base = cs + (size_t)b * CSB + d8 * 8;
    const float4* pe = (const float4*)(base + (size_t)(en + 1) * D_DIM);
    const float4* ps = (const float4*)(base + (size_t)st * D_DIM);
    float4 e0 = pe[0], e1 = pe[1];
    float4 s0 = ps[0], s1 = ps[1];
    us8 o;
    o[0] = f2bf((e0.x - s0.x) * inv);
    o[1] = f2bf((e0.y - s0.y) * inv);
    o[2] = f2bf((e0.z - s0.z) * inv);
    o[3] = f2bf((e0.w - s0.w) * inv);
    o[4] = f2bf((e1.x - s1.x) * inv);
    o[5] = f2bf((e1.y - s1.y) * inv);
    o[6] = f2bf((e1.z - s1.z) * inv);
    o[7] = f2bf((e1.w - s1.w) * inv);
    *(us8*)&rep[(size_t)bs * D_DIM + d8 * 8] = o;
}

// ---------------- Phase 3: GEMM 256x256xBK64 + bias + ReLU ------------------
// M=49152, N=K=1024. 8 waves (2Mx4N), per-wave 128x64 output, acc[8][4].
// LDS 128KB: As/Bs 2x32KB each, double-buffered. One s_barrier per K-tile,
// counted vmcnt ledger (round-6 proven). T2 swizzle via pre-swizzled glds
// source + swizzled ds_read (both-sides involution, rule #21). XCD-bijective
// swizzle keeps the 4 bn-siblings of one bm adjacent -> A-tile HBM-fetched
// once, 3x L2 hits.
__global__ __launch_bounds__(512, 2) void gemm_bias_relu(
    const unsigned short* __restrict__ A,    // rep [M][1024] bf16 bits
    const unsigned short* __restrict__ Wt,   // Wbf [N][1024] bf16 bits
    const float* __restrict__ bias,
    float* __restrict__ out) {
    constexpr int K = D_DIM, N = D_DIM;
    __shared__ __align__(16) unsigned short As[2][256 * 64];   // 64 KB
    __shared__ __align__(16) unsigned short Bs[2][256 * 64];   // 64 KB

    const int tid = threadIdx.x;
    const int wid = tid >> 6, lane = tid & 63;

    // 768 blocks, 96 per XCD; consecutive idx -> consecutive (bm,bn) so the
    // 4 bn-siblings co-reside on one XCD.
    int blk = blockIdx.x;
    int swz = (blk & 7) * 96 + (blk >> 3);
    const int bm = swz >> 2;                  // 0..191
    const int bn = swz & 3;                   // 0..3
    const int rowM = bm * 256;
    const int colN = bn * 256;

    const int fr = lane & 15;
    const int kq = lane >> 4;
    const int wr = wid >> 2, wc = wid & 3;    // 2 x 4 wave grid

    f32x4 acc[8][4];
    #pragma unroll
    for (int i = 0; i < 8; ++i)
        #pragma unroll
        for (int j = 0; j < 4; ++j) acc[i][j] = (f32x4){0.f, 0.f, 0.f, 0.f};

#define FENCE() do { asm volatile("" ::: "memory"); \
                     __builtin_amdgcn_sched_barrier(0); } while (0)

    // Tile: 256 rows x 64 k-elems = 32KB = 2048 16B-chunks; 4 per thread.
    // ci = i*512+tid; row r = ci>>3, chunk c = ci&7. LDS linear at ci*16 B
    // (wave-uniform base + lane*16). Global col chunk pre-swizzled c^(r&7);
    // read side XORs the same -> identity (rule #21).
#define STAGE(k0v, bufi) do { \
        _Pragma("unroll") \
        for (int i = 0; i < 4; ++i) { \
            int ci = i * 512 + tid; \
            int r = ci >> 3, c = ci & 7; \
            int gc = (k0v) + ((c ^ (r & 7)) * 8); \
            const unsigned short* sa = A + (size_t)(rowM + r) * K + gc; \
            __builtin_amdgcn_global_load_lds( \
                (const __attribute__((address_space(1))) void*)sa, \
                (__attribute__((address_space(3))) void*)&As[bufi][(size_t)ci * 8], \
                16, 0, 0); \
            const unsigned short* sb = Wt + (size_t)(colN + r) * K + gc; \
            __builtin_amdgcn_global_load_lds( \
                (const __attribute__((address_space(1))) void*)sb, \
                (__attribute__((address_space(3))) void*)&Bs[bufi][(size_t)ci * 8], \
                16, 0, 0); \
        } \
    } while (0)

#define COMPUTE(bufi) do { \
        _Pragma("unroll") \
        for (int ks = 0; ks < 2; ++ks) { \
            const int kb = ks * 64 + kq * 16; \
            short8 af[8], bq[4]; \
            _Pragma("unroll") \
            for (int i = 0; i < 8; ++i) { \
                int ra = wr * 128 + i * 16 + fr; \
                af[i] = *(const short8*)((const char*)As[bufi] + ra * 128 + (kb ^ ((ra & 7) << 4))); \
            } \
            _Pragma("unroll") \
            for (int j = 0; j < 4; ++j) { \
                int rb = wc * 64 + j * 16 + fr; \
                bq[j] = *(const short8*)((const char*)Bs[bufi] + rb * 128 + (kb ^ ((rb & 7) << 4))); \
            } \
            __builtin_amdgcn_s_setprio(1); \
            _Pragma("unroll") \
            for (int i = 0; i < 8; ++i) \
                _Pragma("unroll") \
                for (int j = 0; j < 4; ++j) \
                    acc[i][j] = __builtin_amdgcn_mfma_f32_16x16x32_bf16(af[i], bq[j], acc[i][j], 0, 0, 0); \
            __builtin_amdgcn_s_setprio(0); \
        } \
    } while (0)

    // prologue
    STAGE(0, 0);                  // 8 glds
    FENCE();
    asm volatile("s_waitcnt vmcnt(0) lgkmcnt(0)" ::: "memory");
    __builtin_amdgcn_s_barrier();
    FENCE();
    STAGE(64, 1);                 // tile 1 in flight across COMPUTE(0)
    FENCE();

    // main loop: one barrier per K-tile; STAGE(t+2) issued right after the
    // barrier into the buffer COMPUTE(t) just released -> full-tile window.
    for (int t = 0; t < 16; ++t) {
        COMPUTE(t & 1);
        if (t < 15) {
            FENCE();
            asm volatile("s_waitcnt vmcnt(0) lgkmcnt(0)" ::: "memory");  // drain STAGE(t+1)
            __builtin_amdgcn_s_barrier();
            FENCE();
            if (t < 14) {
                STAGE((t + 2) * 64, t & 1);
                FENCE();
            }
        }
    }

    // epilogue: C/D layout col=lane&15, row=(lane>>4)*4+r (m89/m91)
    const int m0 = rowM + wr * 128;
    const int n0 = colN + wc * 64;
    float bv[4];
    #pragma unroll
    for (int j = 0; j < 4; ++j) bv[j] = bias[n0 + j * 16 + fr];
    #pragma unroll
    for (int i = 0; i < 8; ++i)
        #pragma unroll
        for (int j = 0; j < 4; ++j)
            #pragma unroll
            for (int r = 0; r < 4; ++r) {
                int m = m0 + i * 16 + kq * 4 + r;
                int n = n0 + j * 16 + fr;
                float v = acc[i][j][r] + bv[j];
                out[(size_t)m * N + n] = v > 0.f ? v : 0.f;
            }
#undef FENCE
#undef STAGE
#undef COMPUTE
}

extern "C" void kernel_launch(void* const* d_in, const int* in_sizes, int n_in,
                              void* d_out, int out_size, void* d_ws, size_t ws_size,
                              hipStream_t stream) {
    const float* h = (const float*)d_in[0];
    const int* span = (const int*)d_in[1];
    const float* W = (const float*)d_in[2];
    const float* bias = (const float*)d_in[3];
    float* out = (float*)d_out;

    char* ws = (char*)d_ws;
    // ws layout (bytes):
    //   cs   : [B][L+1][D] fp32 = 16,809,984    @ 0
    //   Wbf  : [D][D]     bf16 =  2,097,152     @ 16,809,984
    //   csum : [B][8][D]  fp32 =    262,144     @ 18,907,136
    //   rep  : [M][D]     bf16 = 100,663,296    @ 19,169,280
    float* cs = (float*)(ws);
    unsigned short* Wbf = (unsigned short*)(ws + 16809984);
    float* csum = (float*)(ws + 18907136);
    unsigned short* rep = (unsigned short*)(ws + 19169280);

    prep_fused<<<768, 256, 0, stream>>>(h, csum, W, Wbf);
    build_cs<<<256, 256, 0, stream>>>(h, csum, cs);
    spanrep<<<24576, 256, 0, stream>>>(cs, span, rep);
    gemm_bias_relu<<<768, 512, 0, stream>>>(rep, Wbf, bias, out);
}

// Round 8
// 373.901 us; speedup vs baseline: 1.0152x; 1.0152x over previous
//
#include <hip/hip_runtime.h>
#include <hip/hip_bf16.h>
#include <stdint.h>

#define B_DIM 8
#define L_DIM 512
#define D_DIM 1024
#define S_DIM 6144
#define M_DIM (B_DIM * S_DIM)       // 49152
#define NCHUNK 8
#define CHUNK (L_DIM / NCHUNK)      // 64
#define CSB (513 * 1024)            // floats per batch in cs ([L+1][D])

typedef __attribute__((ext_vector_type(8))) short short8;
typedef __attribute__((ext_vector_type(4))) float f32x4;
typedef __attribute__((ext_vector_type(8))) unsigned short us8;

__device__ __forceinline__ unsigned short f2bf(float f) {
    unsigned int u = __float_as_uint(f);
    u += 0x7FFFu + ((u >> 16) & 1u);
    return (unsigned short)(u >> 16);
}

// ---------------- Phase 1a: chunk_sums + wconv fused ----------------
__global__ __launch_bounds__(256) void prep_fused(const float* __restrict__ h,
                                                  float* __restrict__ csum,
                                                  const float* __restrict__ W,
                                                  unsigned short* __restrict__ Wbf) {
    if (blockIdx.x < 256) {
        int tid = blockIdx.x * 256 + threadIdx.x;   // 65536 total
        int d = tid & 1023;
        int c = (tid >> 10) & 7;
        int b = tid >> 13;
        const float* hp = h + ((size_t)b * L_DIM + c * CHUNK) * D_DIM + d;
        float s = 0.f;
        #pragma unroll 8
        for (int i = 0; i < CHUNK; ++i) s += hp[(size_t)i * D_DIM];
        csum[tid] = s;
    } else {
        int tid = (blockIdx.x - 256) * 256 + threadIdx.x;   // 131072 total
        const float4* p = (const float4*)(W + (size_t)tid * 8);
        float4 a = p[0], c = p[1];
        us8 o;
        o[0] = f2bf(a.x); o[1] = f2bf(a.y); o[2] = f2bf(a.z); o[3] = f2bf(a.w);
        o[4] = f2bf(c.x); o[5] = f2bf(c.y); o[6] = f2bf(c.z); o[7] = f2bf(c.w);
        *(us8*)&Wbf[(size_t)tid * 8] = o;
    }
}

// ---------------- Phase 1b: build cs (exclusive prefix, L+1 rows) ----------
__global__ __launch_bounds__(256) void build_cs(const float* __restrict__ h,
                                                const float* __restrict__ csum,
                                                float* __restrict__ cs) {
    int tid = blockIdx.x * 256 + threadIdx.x;   // 65536 total
    int d = tid & 1023;
    int c = (tid >> 10) & 7;
    int b = tid >> 13;
    float p = 0.f;
    for (int cc = 0; cc < c; ++cc)
        p += csum[(b << 13) + (cc << 10) + d];
    const float* hp = h + ((size_t)b * L_DIM + c * CHUNK) * D_DIM + d;
    float* cp = cs + ((size_t)b * (L_DIM + 1) + c * CHUNK) * D_DIM + d;
    if (c == 0) cp[0] = 0.f;
    #pragma unroll 8
    for (int i = 0; i < CHUNK; ++i) {
        p += hp[(size_t)i * D_DIM];
        cp[(size_t)(i + 1) * D_DIM] = p;
    }
}

// ---------------- Phase 2: span_rep -> bf16 ----------------
__global__ __launch_bounds__(256) void spanrep(const float* __restrict__ cs,
                                               const int* __restrict__ span_idx,
                                               unsigned short* __restrict__ rep) {
    int tid = blockIdx.x * 256 + threadIdx.x;   // 6,291,456 total
    int d8 = tid & 127;
    int bs = tid >> 7;                           // 0..49151
    int b = bs / S_DIM;
    int2 se = ((const int2*)span_idx)[bs];
    int st = min(max(se.x, 0), L_DIM - 1);
    int en = min(max(se.y, 0), L_DIM - 1);
    bool valid = st <= en;
    float inv = valid ? 1.0f / (float)(en - st + 1) : 0.0f;
    const float* base = cs + (size_t)b * CSB + d8 * 8;
    const float4* pe = (const float4*)(base + (size_t)(en + 1) * D_DIM);
    const float4* ps = (const float4*)(base + (size_t)st * D_DIM);
    float4 e0 = pe[0], e1 = pe[1];
    float4 s0 = ps[0], s1 = ps[1];
    us8 o;
    o[0] = f2bf((e0.x - s0.x) * inv);
    o[1] = f2bf((e0.y - s0.y) * inv);
    o[2] = f2bf((e0.z - s0.z) * inv);
    o[3] = f2bf((e0.w - s0.w) * inv);
    o[4] = f2bf((e1.x - s1.x) * inv);
    o[5] = f2bf((e1.y - s1.y) * inv);
    o[6] = f2bf((e1.z - s1.z) * inv);
    o[7] = f2bf((e1.w - s1.w) * inv);
    *(us8*)&rep[(size_t)bs * D_DIM + d8 * 8] = o;
}

// ---------------- Phase 3: GEMM 256x256, ring-4 half-K pipeline -------------
// M=49152, N=K=1024. 8 waves (2M x 4N), per-wave 128x64 out, acc[8][4].
// LDS: 4 slots x (A 256x32 + B 256x32) = 128 KB. 32 half-K phases; per phase:
// 12 ds_read_b128 | STAGE(g+3) 4 glds | lgkmcnt(0) | 32 MFMA | vmcnt(8) | bar.
// Prefetch depth 3 phases; vmcnt never 0 until epilogue (T4).
// Bank perm: 16B chunk c_phys = c ^ (r&3) ^ ((r>>2)&1) — spreads 16 rows over
// all 8 bank-chunks (2 lanes/chunk = free). Applied on glds SOURCE and
// ds_read identically (both-sides involution, rule #21).
__global__ __launch_bounds__(512, 2) void gemm_bias_relu(
    const unsigned short* __restrict__ A,    // rep [M][1024] bf16 bits
    const unsigned short* __restrict__ Wt,   // Wbf [N][1024] bf16 bits
    const float* __restrict__ bias,
    float* __restrict__ out) {
    constexpr int K = D_DIM, N = D_DIM;
    __shared__ __align__(16) unsigned short AsL[4 * 8192];   // 64 KB
    __shared__ __align__(16) unsigned short BsL[4 * 8192];   // 64 KB

    const int tid = threadIdx.x;
    const int wid = tid >> 6, lane = tid & 63;

    // 768 blocks, 96/XCD; 4 bn-siblings of one bm adjacent on one XCD.
    int blk = blockIdx.x;
    int swz = (blk & 7) * 96 + (blk >> 3);
    const int bm = swz >> 2;                  // 0..191
    const int bn = swz & 3;                   // 0..3
    const int rowM = bm * 256;
    const int colN = bn * 256;

    const int fr = lane & 15;
    const int kq = lane >> 4;                 // 0..3 (16B chunk within 32-k)
    const int wr = wid >> 2, wc = wid & 3;    // 2 x 4 wave grid

    // per-lane ds_read byte offsets within a slot (static after unroll)
    int aoff[8], boff[4];
    #pragma unroll
    for (int i = 0; i < 8; ++i) {
        int r = wr * 128 + i * 16 + fr;
        aoff[i] = r * 64 + (((kq ^ (r & 3) ^ ((r >> 2) & 1))) << 4);
    }
    #pragma unroll
    for (int j = 0; j < 4; ++j) {
        int r = wc * 64 + j * 16 + fr;
        boff[j] = r * 64 + (((kq ^ (r & 3) ^ ((r >> 2) & 1))) << 4);
    }

    f32x4 acc[8][4];
    #pragma unroll
    for (int i = 0; i < 8; ++i)
        #pragma unroll
        for (int j = 0; j < 4; ++j) acc[i][j] = (f32x4){0.f, 0.f, 0.f, 0.f};

    // STAGE(g): 1024 16B-chunks per operand; thread does 2 A + 2 B glds.
    // ci -> (r = ci>>2, c_phys = ci&3); source supplies c_log = c_phys ^ perm.
#define STAGE(gg) do { \
        const int kb_ = (gg) * 32; \
        const int sl_ = ((gg) & 3) * 8192; \
        _Pragma("unroll") \
        for (int i_ = 0; i_ < 2; ++i_) { \
            int ci_ = i_ * 512 + tid; \
            int r_ = ci_ >> 2, cp_ = ci_ & 3; \
            int cl_ = cp_ ^ (r_ & 3) ^ ((r_ >> 2) & 1); \
            const unsigned short* sa_ = A + (size_t)(rowM + r_) * K + kb_ + cl_ * 8; \
            __builtin_amdgcn_global_load_lds( \
                (const __attribute__((address_space(1))) void*)sa_, \
                (__attribute__((address_space(3))) void*)&AsL[sl_ + ci_ * 8], \
                16, 0, 0); \
            const unsigned short* sb_ = Wt + (size_t)(colN + r_) * K + kb_ + cl_ * 8; \
            __builtin_amdgcn_global_load_lds( \
                (const __attribute__((address_space(1))) void*)sb_, \
                (__attribute__((address_space(3))) void*)&BsL[sl_ + ci_ * 8], \
                16, 0, 0); \
        } \
    } while (0)

#define PHASE(gg, DOSTAGE) do { \
        short8 af_[8]; short8 bq_[4]; \
        const char* ab_ = ((const char*)AsL) + ((gg) & 3) * 16384; \
        const char* bb_ = ((const char*)BsL) + ((gg) & 3) * 16384; \
        _Pragma("unroll") \
        for (int i_ = 0; i_ < 8; ++i_) af_[i_] = *(const short8*)(ab_ + aoff[i_]); \
        _Pragma("unroll") \
        for (int j_ = 0; j_ < 4; ++j_) bq_[j_] = *(const short8*)(bb_ + boff[j_]); \
        if (DOSTAGE) STAGE((gg) + 3); \
        asm volatile("s_waitcnt lgkmcnt(0)" ::: "memory"); \
        __builtin_amdgcn_sched_barrier(0); \
        __builtin_amdgcn_s_setprio(1); \
        _Pragma("unroll") \
        for (int i_ = 0; i_ < 8; ++i_) \
            _Pragma("unroll") \
            for (int j_ = 0; j_ < 4; ++j_) \
                acc[i_][j_] = __builtin_amdgcn_mfma_f32_16x16x32_bf16( \
                    af_[i_], bq_[j_], acc[i_][j_], 0, 0, 0); \
        __builtin_amdgcn_s_setprio(0); \
    } while (0)

    // prologue: 3 slots in flight (12 loads); slot0 ready at vmcnt(8)
    STAGE(0);
    STAGE(1);
    STAGE(2);
    asm volatile("s_waitcnt vmcnt(8)" ::: "memory");
    __builtin_amdgcn_s_barrier();

    // main: phases 0..28 uniform (stage g+3, vmcnt(8) -> slot g+1 ready)
    #pragma unroll 4
    for (int g = 0; g < 29; ++g) {
        PHASE(g, 1);
        asm volatile("s_waitcnt vmcnt(8)" ::: "memory");
        __builtin_amdgcn_s_barrier();
    }
    // tail: outstanding stages 30,31 -> vmcnt(4); then 31 -> vmcnt(0)
    PHASE(29, 0);
    asm volatile("s_waitcnt vmcnt(4)" ::: "memory");
    __builtin_amdgcn_s_barrier();
    PHASE(30, 0);
    asm volatile("s_waitcnt vmcnt(0)" ::: "memory");
    __builtin_amdgcn_s_barrier();
    PHASE(31, 0);

    // epilogue: C/D layout col=lane&15, row=(lane>>4)*4+r (m89/m91)
    const int m0 = rowM + wr * 128;
    const int n0 = colN + wc * 64;
    float bv[4];
    #pragma unroll
    for (int j = 0; j < 4; ++j) bv[j] = bias[n0 + j * 16 + fr];
    #pragma unroll
    for (int i = 0; i < 8; ++i)
        #pragma unroll
        for (int j = 0; j < 4; ++j)
            #pragma unroll
            for (int r = 0; r < 4; ++r) {
                int m = m0 + i * 16 + kq * 4 + r;
                int n = n0 + j * 16 + fr;
                float v = acc[i][j][r] + bv[j];
                out[(size_t)m * N + n] = v > 0.f ? v : 0.f;
            }
#undef STAGE
#undef PHASE
}

extern "C" void kernel_launch(void* const* d_in, const int* in_sizes, int n_in,
                              void* d_out, int out_size, void* d_ws, size_t ws_size,
                              hipStream_t stream) {
    const float* h = (const float*)d_in[0];
    const int* span = (const int*)d_in[1];
    const float* W = (const float*)d_in[2];
    const float* bias = (const float*)d_in[3];
    float* out = (float*)d_out;

    char* ws = (char*)d_ws;
    // ws layout (bytes):
    //   cs   : [B][L+1][D] fp32 = 16,809,984    @ 0
    //   Wbf  : [D][D]     bf16 =  2,097,152     @ 16,809,984
    //   csum : [B][8][D]  fp32 =    262,144     @ 18,907,136
    //   rep  : [M][D]     bf16 = 100,663,296    @ 19,169,280
    float* cs = (float*)(ws);
    unsigned short* Wbf = (unsigned short*)(ws + 16809984);
    float* csum = (float*)(ws + 18907136);
    unsigned short* rep = (unsigned short*)(ws + 19169280);

    prep_fused<<<768, 256, 0, stream>>>(h, csum, W, Wbf);
    build_cs<<<256, 256, 0, stream>>>(h, csum, cs);
    spanrep<<<24576, 256, 0, stream>>>(cs, span, rep);
    gemm_bias_relu<<<768, 512, 0, stream>>>(rep, Wbf, bias, out);
}